// Round 5
// baseline (16759.322 us; speedup 1.0000x reference)
//
#include <hip/hip_runtime.h>
#include <cmath>

#define B_ 32
#define S_ 128
#define T_ 64
#define STEPS_ 63
#define V_ 32000
#define E_ 512
#define H_ 512

typedef __attribute__((ext_vector_type(4))) float f32x4;
typedef __attribute__((ext_vector_type(8))) short bf16x8;

__device__ inline short f2bf(float x) {
  unsigned u = __builtin_bit_cast(unsigned, x);
  u = (u + 0x7fffu + ((u >> 16) & 1u)) >> 16;
  return (short)u;
}
__device__ inline float bf2f(short h) {
  unsigned u = ((unsigned)(unsigned short)h) << 16;
  return __builtin_bit_cast(float, u);
}

// ---------------- transpose: src[R][C] -> dst[C][R] ----------------
__global__ void k_transpose(const float* __restrict__ src, float* __restrict__ dst,
                            int R, int C) {
  __shared__ float tile[32][33];
  int c0 = blockIdx.x * 32, r0 = blockIdx.y * 32;
  int tx = threadIdx.x, ty = threadIdx.y;  // (32, 8)
#pragma unroll
  for (int i = 0; i < 32; i += 8) {
    int r = r0 + ty + i, c = c0 + tx;
    if (r < R && c < C) tile[ty + i][tx] = src[(long)r * C + c];
  }
  __syncthreads();
#pragma unroll
  for (int i = 0; i < 32; i += 8) {
    int c = c0 + ty + i, r = r0 + tx;
    if (r < R && c < C) dst[(long)c * R + r] = tile[tx][ty + i];
  }
}

// ---------------- MFMA bf16 split-precision GEMM (R1/R2-proven) ----------------
__global__ __launch_bounds__(256) void k_mfma_gemm(
    const float* __restrict__ A, const float* __restrict__ emb,
    const int* __restrict__ tok, int amode,
    const float* __restrict__ Bmat, long ldb,
    const float* __restrict__ bias,
    float* __restrict__ out, long sb, long st,
    int M, int N, int K) {
  __shared__ short Ah[128 * 40];
  __shared__ short Al[128 * 40];
  __shared__ short Bh[128 * 40];
  __shared__ short Bl[128 * 40];
  int t = threadIdx.x;
  int n0 = blockIdx.x * 128, m0 = blockIdx.y * 128;
  int ar = t >> 2, ac = (t & 3) * 8;

  const float* arow0;
  const float* arow1;
  {
    int m = m0 + ar;       int mc = m < M ? m : M - 1;
    int m2 = m0 + ar + 64; int mc2 = m2 < M ? m2 : M - 1;
    if (amode == 0) {
      arow0 = A + (long)mc * K;
      arow1 = A + (long)mc2 * K;
    } else {
      int b = mc & 31, q = mc >> 5;
      int tk = (amode == 1) ? tok[b * S_ + q] : tok[b * T_ + q];
      arow0 = emb + (long)tk * K;
      b = mc2 & 31; q = mc2 >> 5;
      tk = (amode == 1) ? tok[b * S_ + q] : tok[b * T_ + q];
      arow1 = emb + (long)tk * K;
    }
  }
  const float* brow0 = Bmat + (long)(n0 + ar) * ldb;
  const float* brow1 = Bmat + (long)(n0 + ar + 64) * ldb;

  int lane = t & 63, wave = t >> 6;
  int wm = (wave >> 1) * 64, wn = (wave & 1) * 64;
  int lr = lane & 15, lk = lane >> 4;
  f32x4 acc[4][4] = {};

  for (int k0 = 0; k0 < K; k0 += 32) {
    auto stage = [&](const float* rowp, short* Dh, short* Dl, int r) {
      float4 x0 = *(const float4*)(rowp + k0 + ac);
      float4 x1 = *(const float4*)(rowp + k0 + ac + 4);
      float xs[8] = {x0.x, x0.y, x0.z, x0.w, x1.x, x1.y, x1.z, x1.w};
      bf16x8 hi, lo;
#pragma unroll
      for (int i = 0; i < 8; ++i) {
        short h = f2bf(xs[i]);
        hi[i] = h;
        lo[i] = f2bf(xs[i] - bf2f(h));
      }
      *(bf16x8*)&Dh[r * 40 + ac] = hi;
      *(bf16x8*)&Dl[r * 40 + ac] = lo;
    };
    stage(arow0, Ah, Al, ar);
    stage(arow1, Ah, Al, ar + 64);
    stage(brow0, Bh, Bl, ar);
    stage(brow1, Bh, Bl, ar + 64);
    __syncthreads();

    bf16x8 a_h[4], a_l[4], b_h[4], b_l[4];
#pragma unroll
    for (int i = 0; i < 4; ++i) {
      int ra = (wm + i * 16 + lr) * 40 + lk * 8;
      a_h[i] = *(const bf16x8*)&Ah[ra];
      a_l[i] = *(const bf16x8*)&Al[ra];
      int rb = (wn + i * 16 + lr) * 40 + lk * 8;
      b_h[i] = *(const bf16x8*)&Bh[rb];
      b_l[i] = *(const bf16x8*)&Bl[rb];
    }
#pragma unroll
    for (int i = 0; i < 4; ++i)
#pragma unroll
      for (int j = 0; j < 4; ++j) {
        acc[i][j] = __builtin_amdgcn_mfma_f32_16x16x32_bf16(a_l[i], b_h[j], acc[i][j], 0, 0, 0);
        acc[i][j] = __builtin_amdgcn_mfma_f32_16x16x32_bf16(a_h[i], b_l[j], acc[i][j], 0, 0, 0);
        acc[i][j] = __builtin_amdgcn_mfma_f32_16x16x32_bf16(a_h[i], b_h[j], acc[i][j], 0, 0, 0);
      }
    __syncthreads();
  }

#pragma unroll
  for (int i = 0; i < 4; ++i) {
#pragma unroll
    for (int r = 0; r < 4; ++r) {
      int m = m0 + wm + i * 16 + lk * 4 + r;
      if (m >= M) continue;
      long base = (long)(m & 31) * sb + (long)(m >> 5) * st;
#pragma unroll
      for (int j = 0; j < 4; ++j) {
        int n = n0 + wn + j * 16 + lr;
        out[base + n] = acc[i][j][r] + bias[n];
      }
    }
  }
}

// ---------------- block-local encoder: 32 blocks (one per b), 128 steps ----------------
__global__ __launch_bounds__(256) void k_enc_all(
    const float* __restrict__ gi_all,  // [S*B][1536], row = s*32+b (bih folded)
    const float* __restrict__ WhhT,    // [512][1536]
    const float* __restrict__ bhh,
    const int* __restrict__ lens,
    float* __restrict__ h_out,         // [32][512] final hidden
    float* __restrict__ EO) {          // [32][128][512]
  __shared__ __align__(16) float hs[512];
  int b = blockIdx.x;
  int t = threadIdx.x;
  int u0 = 2 * t;  // units u0, u0+1
  int len = lens[b];
  float2 br = *(const float2*)(bhh + u0);
  float2 bz = *(const float2*)(bhh + 512 + u0);
  float2 bn = *(const float2*)(bhh + 1024 + u0);
  hs[u0] = 0.f;
  hs[u0 + 1] = 0.f;
  __syncthreads();

  for (int s = 0; s < S_; ++s) {
    float ar0 = br.x, ar1 = br.y, az0 = bz.x, az1 = bz.y, an0 = bn.x, an1 = bn.y;
    for (int k = 0; k < 512; k += 2) {
      float hk0 = hs[k], hk1 = hs[k + 1];
      const float* w0 = WhhT + (long)k * 1536 + u0;
      const float* w1 = w0 + 1536;
      float2 wr0 = *(const float2*)(w0);
      float2 wz0 = *(const float2*)(w0 + 512);
      float2 wn0 = *(const float2*)(w0 + 1024);
      float2 wr1 = *(const float2*)(w1);
      float2 wz1 = *(const float2*)(w1 + 512);
      float2 wn1 = *(const float2*)(w1 + 1024);
      ar0 += hk0 * wr0.x + hk1 * wr1.x;  ar1 += hk0 * wr0.y + hk1 * wr1.y;
      az0 += hk0 * wz0.x + hk1 * wz1.x;  az1 += hk0 * wz0.y + hk1 * wz1.y;
      an0 += hk0 * wn0.x + hk1 * wn1.x;  an1 += hk0 * wn0.y + hk1 * wn1.y;
    }
    const float* gi = gi_all + ((long)s * 32 + b) * 1536;
    float2 gr = *(const float2*)(gi + u0);
    float2 gz = *(const float2*)(gi + 512 + u0);
    float2 gn = *(const float2*)(gi + 1024 + u0);
    float r0 = 1.f / (1.f + expf(-(gr.x + ar0)));
    float r1 = 1.f / (1.f + expf(-(gr.y + ar1)));
    float z0 = 1.f / (1.f + expf(-(gz.x + az0)));
    float z1 = 1.f / (1.f + expf(-(gz.y + az1)));
    float n0 = tanhf(gn.x + r0 * an0);
    float n1 = tanhf(gn.y + r1 * an1);
    float hold0 = hs[u0], hold1 = hs[u0 + 1];
    float hn0 = (1.f - z0) * n0 + z0 * hold0;
    float hn1 = (1.f - z1) * n1 + z1 * hold1;
    bool valid = s < len;
    *(float2*)(EO + ((long)b * 128 + s) * 512 + u0) =
        make_float2(valid ? hn0 : 0.f, valid ? hn1 : 0.f);
    __syncthreads();  // all reads of old hs complete
    hs[u0] = valid ? hn0 : hold0;
    hs[u0 + 1] = valid ? hn1 : hold1;
    __syncthreads();
  }
  *(float2*)(h_out + b * 512 + u0) = make_float2(hs[u0], hs[u0 + 1]);
}

// ---------------- block-local decoder: 32 blocks (one per b), 63 steps ----------------
__global__ __launch_bounds__(256) void k_dec_all(
    const float* __restrict__ gie,   // [STEPS*B][1536], row = t*32+b (e-part + bih)
    const float* __restrict__ EO,    // [32][128][512]
    const float* __restrict__ WihT,  // [1024][1536], ctx part = rows 512..1023
    const float* __restrict__ WhhT,  // [512][1536]
    const float* __restrict__ bhh,
    const int* __restrict__ lens,
    const float* __restrict__ WcT,   // [1024][512]
    const float* __restrict__ bc,
    const float* __restrict__ h_init,  // [32][512]
    float* __restrict__ ccall,         // [STEPS*32][512], row = step*32+b
    float* __restrict__ attns) {       // [32][STEPS][128]
  __shared__ __align__(16) float hs[512];
  __shared__ __align__(16) float cs[512];
  __shared__ __align__(16) float sc[128];
  __shared__ float wred[8];
  int b = blockIdx.x;
  int t = threadIdx.x;
  int lane = t & 63, wave = t >> 6;
  int u0 = 2 * t;
  int len = lens[b];
  float2 br = *(const float2*)(bhh + u0);
  float2 bz = *(const float2*)(bhh + 512 + u0);
  float2 bn = *(const float2*)(bhh + 1024 + u0);
  float2 bcc = *(const float2*)(bc + u0);
  ((float2*)hs)[t] = ((const float2*)(h_init + b * 512))[t];
  __syncthreads();
  const float4* EOb = (const float4*)(EO + (long)b * 128 * 512);

  for (int step = 0; step < STEPS_; ++step) {
    // ---- attention scores: wave w handles s = w*32..w*32+31 ----
    float4 h1 = ((const float4*)hs)[lane * 2];
    float4 h2 = ((const float4*)hs)[lane * 2 + 1];
    for (int si = 0; si < 32; ++si) {
      int s = wave * 32 + si;
      const float4* er = EOb + (long)s * 128;
      float4 e1 = er[lane * 2], e2 = er[lane * 2 + 1];
      float p = e1.x * h1.x + e1.y * h1.y + e1.z * h1.z + e1.w * h1.w +
                e2.x * h2.x + e2.y * h2.y + e2.z * h2.z + e2.w * h2.w;
#pragma unroll
      for (int off = 32; off > 0; off >>= 1) p += __shfl_down(p, off, 64);
      if (lane == 0) sc[s] = p;
    }
    __syncthreads();
    // ---- softmax over s<len ----
    float v = (t < 128) ? ((t < len) ? sc[t] : -INFINITY) : -INFINITY;
    float wm = v;
#pragma unroll
    for (int off = 32; off > 0; off >>= 1) wm = fmaxf(wm, __shfl_down(wm, off, 64));
    if (lane == 0) wred[wave] = wm;
    __syncthreads();
    float m = fmaxf(fmaxf(wred[0], wred[1]), fmaxf(wred[2], wred[3]));
    float e = (t < 128 && t < len) ? expf(sc[t] - m) : 0.f;
    float wsum = e;
#pragma unroll
    for (int off = 32; off > 0; off >>= 1) wsum += __shfl_down(wsum, off, 64);
    if (lane == 0) wred[4 + wave] = wsum;
    __syncthreads();
    float ssum = wred[4] + wred[5] + wred[6] + wred[7];
    float aw = e / ssum;
    if (t < 128) {
      sc[t] = aw;
      attns[((long)b * STEPS_ + step) * 128 + t] = aw;
    }
    __syncthreads();
    // ---- ctx[jj] = sum_s aw[s] * EO[b][s][jj] ----
    for (int jj = t; jj < 512; jj += 256) {
      float acc = 0.f;
      for (int s = 0; s < 128; ++s) acc += sc[s] * EO[((long)b * 128 + s) * 512 + jj];
      cs[jj] = acc;
    }
    __syncthreads();
    // ---- GRU cell: thread t computes units u0, u0+1 ----
    float ar0 = br.x, ar1 = br.y, az0 = bz.x, az1 = bz.y, an0 = bn.x, an1 = bn.y;
    float gr0 = 0.f, gr1 = 0.f, gz0 = 0.f, gz1 = 0.f, gn0 = 0.f, gn1 = 0.f;
    for (int k = 0; k < 512; k += 2) {
      float hk0 = hs[k], hk1 = hs[k + 1];
      float ck0 = cs[k], ck1 = cs[k + 1];
      const float* wh0 = WhhT + (long)k * 1536 + u0;
      const float* wh1 = wh0 + 1536;
      const float* wc0 = WihT + (long)(512 + k) * 1536 + u0;
      const float* wc1 = wc0 + 1536;
      float2 whr0 = *(const float2*)(wh0);
      float2 whz0 = *(const float2*)(wh0 + 512);
      float2 whn0 = *(const float2*)(wh0 + 1024);
      float2 whr1 = *(const float2*)(wh1);
      float2 whz1 = *(const float2*)(wh1 + 512);
      float2 whn1 = *(const float2*)(wh1 + 1024);
      ar0 += hk0 * whr0.x + hk1 * whr1.x;  ar1 += hk0 * whr0.y + hk1 * whr1.y;
      az0 += hk0 * whz0.x + hk1 * whz1.x;  az1 += hk0 * whz0.y + hk1 * whz1.y;
      an0 += hk0 * whn0.x + hk1 * whn1.x;  an1 += hk0 * whn0.y + hk1 * whn1.y;
      float2 wcr0 = *(const float2*)(wc0);
      float2 wcz0 = *(const float2*)(wc0 + 512);
      float2 wcn0 = *(const float2*)(wc0 + 1024);
      float2 wcr1 = *(const float2*)(wc1);
      float2 wcz1 = *(const float2*)(wc1 + 512);
      float2 wcn1 = *(const float2*)(wc1 + 1024);
      gr0 += ck0 * wcr0.x + ck1 * wcr1.x;  gr1 += ck0 * wcr0.y + ck1 * wcr1.y;
      gz0 += ck0 * wcz0.x + ck1 * wcz1.x;  gz1 += ck0 * wcz0.y + ck1 * wcz1.y;
      gn0 += ck0 * wcn0.x + ck1 * wcn1.x;  gn1 += ck0 * wcn0.y + ck1 * wcn1.y;
    }
    const float* gi = gie + ((long)step * 32 + b) * 1536;
    float2 gir = *(const float2*)(gi + u0);
    float2 giz = *(const float2*)(gi + 512 + u0);
    float2 gin = *(const float2*)(gi + 1024 + u0);
    float r0 = 1.f / (1.f + expf(-(gir.x + gr0 + ar0)));
    float r1 = 1.f / (1.f + expf(-(gir.y + gr1 + ar1)));
    float z0 = 1.f / (1.f + expf(-(giz.x + gz0 + az0)));
    float z1 = 1.f / (1.f + expf(-(giz.y + gz1 + az1)));
    float n0 = tanhf(gin.x + gn0 + r0 * an0);
    float n1 = tanhf(gin.y + gn1 + r1 * an1);
    float hold0 = hs[u0], hold1 = hs[u0 + 1];
    float hn0 = (1.f - z0) * n0 + z0 * hold0;
    float hn1 = (1.f - z1) * n1 + z1 * hold1;
    __syncthreads();  // all cell reads of old hs complete
    hs[u0] = hn0;
    hs[u0 + 1] = hn1;
    __syncthreads();
    // ---- cc = tanh([hn, ctx] @ Wc.T + bc): thread t -> outputs u0, u0+1 ----
    float c0 = bcc.x, c1 = bcc.y;
    for (int k = 0; k < 512; ++k) {
      float hk = hs[k];
      float ck = cs[k];
      float2 w1 = *(const float2*)(WcT + (long)k * 512 + u0);
      float2 w2 = *(const float2*)(WcT + (long)(512 + k) * 512 + u0);
      c0 += hk * w1.x + ck * w2.x;
      c1 += hk * w1.y + ck * w2.y;
    }
    *(float2*)(ccall + ((long)step * 32 + b) * 512 + u0) =
        make_float2(tanhf(c0), tanhf(c1));
    __syncthreads();  // cs reads done before next step overwrites
  }
}

extern "C" void kernel_launch(void* const* d_in, const int* in_sizes, int n_in,
                              void* d_out, int out_size, void* d_ws, size_t ws_size,
                              hipStream_t stream) {
  (void)in_sizes; (void)n_in; (void)out_size; (void)ws_size;
  const int*   src   = (const int*)d_in[0];
  const int*   lens  = (const int*)d_in[1];
  const int*   tgt   = (const int*)d_in[2];
  const float* emb_e = (const float*)d_in[3];
  const float* Wih_e = (const float*)d_in[4];
  const float* Whh_e = (const float*)d_in[5];
  const float* bih_e = (const float*)d_in[6];
  const float* bhh_e = (const float*)d_in[7];
  const float* emb_d = (const float*)d_in[8];
  const float* Wih_d = (const float*)d_in[9];
  const float* Whh_d = (const float*)d_in[10];
  const float* bih_d = (const float*)d_in[11];
  const float* bhh_d = (const float*)d_in[12];
  const float* Wc    = (const float*)d_in[13];
  const float* bc    = (const float*)d_in[14];
  const float* Wo    = (const float*)d_in[15];
  const float* bo    = (const float*)d_in[16];

  float* logits = (float*)d_out;
  float* attns  = (float*)d_out + (long)B_ * STEPS_ * V_;

  float* w = (float*)d_ws;
  float* WihT_d = w;                   // 1024 x 1536
  float* WhhT_e = WihT_d + 1572864;    // 512 x 1536
  float* WhhT_d = WhhT_e + 786432;     // 512 x 1536
  float* WcT    = WhhT_d + 786432;     // 1024 x 512
  float* GIe    = WcT + 524288;        // 4096 x 1536
  float* GId    = GIe + 6291456;       // 2016(+pad) x 1536
  float* EO     = GId + 3145728;       // 32 x 128 x 512
  float* h0     = EO + 2097152;        // 32 x 512 (final encoder h)
  float* ccall  = h0 + 16384;          // 2016 x 512

  dim3 tb(32, 8);
  k_transpose<<<dim3(1024 / 32, 1536 / 32), tb, 0, stream>>>(Wih_d, WihT_d, 1536, 1024);
  k_transpose<<<dim3(512 / 32, 1536 / 32), tb, 0, stream>>>(Whh_e, WhhT_e, 1536, 512);
  k_transpose<<<dim3(512 / 32, 1536 / 32), tb, 0, stream>>>(Whh_d, WhhT_d, 1536, 512);
  k_transpose<<<dim3(1024 / 32, 512 / 32), tb, 0, stream>>>(Wc, WcT, 512, 1024);

  // GIe[s*32+b][:] = emb_enc[src[b,s]] @ Wih_e^T + bih_e
  k_mfma_gemm<<<dim3(1536 / 128, 4096 / 128), 256, 0, stream>>>(
      nullptr, emb_e, src, 1, Wih_e, 512, bih_e, GIe, 1536L, 32L * 1536L, 4096, 1536, 512);
  // GId[t*32+b][:] = emb_dec[tgt[b,t]] @ Wih_d[:, :512]^T + bih_d
  k_mfma_gemm<<<dim3(1536 / 128, (2016 + 127) / 128), 256, 0, stream>>>(
      nullptr, emb_d, tgt, 2, Wih_d, 1024, bih_d, GId, 1536L, 32L * 1536L, 2016, 1536, 512);

  k_enc_all<<<32, 256, 0, stream>>>(GIe, WhhT_e, bhh_e, lens, h0, EO);

  k_dec_all<<<32, 256, 0, stream>>>(GId, EO, WihT_d, WhhT_d, bhh_d, lens, WcT, bc,
                                    h0, ccall, attns);

  // logits: A = ccall [2016][512], B = Wo [32000][512] (k-major already)
  k_mfma_gemm<<<dim3(V_ / 128, (2016 + 127) / 128), 256, 0, stream>>>(
      ccall, nullptr, nullptr, 0, Wo, 512, bo, logits,
      (long)STEPS_ * V_, (long)V_, 2016, 32000, 512);
}